// Round 3
// baseline (334.038 us; speedup 1.0000x reference)
//
#include <hip/hip_runtime.h>
#include <hip/hip_bf16.h>
#include <math.h>

#define DD 64
#define SCAN_ELEMS 2048

// K1: Wh = H @ W_node^T   (N x 64) = (N x 64) @ (64 x 64)^T
__global__ __launch_bounds__(256) void k_gemm_wh(const float* __restrict__ H,
                                                 const float* __restrict__ W,
                                                 float* __restrict__ Wh, int N) {
  __shared__ float Ws[64][65];  // Ws[k][j] = W[j][k]  (padded: conflict-free)
  __shared__ float Hs[64][64];
  int tid = threadIdx.x;
  int rowBase = blockIdx.x * 64;
  for (int i = tid; i < 4096; i += 256) {
    int j = i >> 6, k = i & 63;
    Ws[k][j] = W[i];
  }
  for (int i = tid; i < 4096; i += 256) {
    int r = i >> 6, k = i & 63;
    int gr = rowBase + r;
    Hs[r][k] = (gr < N) ? H[(size_t)gr * DD + k] : 0.f;
  }
  __syncthreads();
  int c = tid & 63;          // output column (lane)
  int wrow = (tid >> 6) * 16; // 16 rows per wave
  float acc[16];
#pragma unroll
  for (int i = 0; i < 16; ++i) acc[i] = 0.f;
  for (int k = 0; k < 64; ++k) {
    float wv = Ws[k][c];
#pragma unroll
    for (int rr = 0; rr < 16; ++rr) acc[rr] += Hs[wrow + rr][k] * wv;  // Hs: broadcast
  }
  for (int rr = 0; rr < 16; ++rr) {
    int gr = rowBase + wrow + rr;
    if (gr < N) Wh[(size_t)gr * DD + c] = acc[rr];
  }
}

// K1b: s1[n] = Wh[n] . a[0:64],  s2[n] = Wh[n] . a[64:128]   (one wave per node)
__global__ __launch_bounds__(256) void k_s12(const float* __restrict__ Wh,
                                             const float* __restrict__ attvec,
                                             float* __restrict__ s1,
                                             float* __restrict__ s2, int N) {
  int wave = (int)((blockIdx.x * 256 + threadIdx.x) >> 6);
  int lane = threadIdx.x & 63;
  if (wave >= N) return;
  float v = Wh[(size_t)wave * DD + lane];
  float p1 = v * attvec[lane];
  float p2 = v * attvec[64 + lane];
  for (int o = 32; o; o >>= 1) {
    p1 += __shfl_xor(p1, o);
    p2 += __shfl_xor(p2, o);
  }
  if (lane == 0) { s1[wave] = p1; s2[wave] = p2; }
}

// K2: tbl[r][d] = rel_emb[r] . W_rel[d],  t[r] = tbl[r] . a[128:192]
__global__ __launch_bounds__(64) void k_rel(const float* __restrict__ rel_emb,
                                            const float* __restrict__ Wrel,
                                            const float* __restrict__ attvec,
                                            float* __restrict__ tbl,
                                            float* __restrict__ tvec) {
  int r = blockIdx.x;
  int d = threadIdx.x;  // 64 threads
  __shared__ float re[64];
  re[d] = rel_emb[r * DD + d];
  __syncthreads();
  float acc = 0.f;
  for (int k = 0; k < DD; ++k) acc += re[k] * Wrel[d * DD + k];
  tbl[r * DD + d] = acc;
  float p = acc * attvec[128 + d];
  for (int o = 32; o; o >>= 1) p += __shfl_xor(p, o);
  if (d == 0) tvec[r] = p;
}

// K3: histogram of src
__global__ void k_hist(const int* __restrict__ src, int* __restrict__ counts, int E) {
  int i = blockIdx.x * blockDim.x + threadIdx.x;
  if (i < E) atomicAdd(&counts[src[i]], 1);
}

// K4a: per-block exclusive scan over 2048 elements; write partials + block sums
__global__ __launch_bounds__(256) void k_scan_a(const int* __restrict__ counts,
                                                int* __restrict__ partial,
                                                int* __restrict__ blockSums, int N) {
  __shared__ int ts[256];
  int tid = threadIdx.x;
  int base = blockIdx.x * SCAN_ELEMS + tid * 8;
  int v[8];
  int s = 0;
#pragma unroll
  for (int i = 0; i < 8; ++i) {
    int idx = base + i;
    v[i] = (idx < N) ? counts[idx] : 0;
    s += v[i];
  }
  ts[tid] = s;
  __syncthreads();
  for (int off = 1; off < 256; off <<= 1) {
    int val = (tid >= off) ? ts[tid - off] : 0;
    __syncthreads();
    ts[tid] += val;
    __syncthreads();
  }
  int thrExcl = (tid == 0) ? 0 : ts[tid - 1];
  if (tid == 255) blockSums[blockIdx.x] = ts[255];
  int run = thrExcl;
#pragma unroll
  for (int i = 0; i < 8; ++i) {
    int idx = base + i;
    if (idx < N) partial[idx] = run;
    run += v[i];
  }
}

// K4b: exclusive scan of block sums (single wave, chunked with carry)
__global__ __launch_bounds__(64) void k_scan_b(int* __restrict__ blockSums, int nblk) {
  int lane = threadIdx.x;
  int carry = 0;
  for (int b = 0; b < nblk; b += 64) {
    int i = b + lane;
    int v = (i < nblk) ? blockSums[i] : 0;
    for (int off = 1; off < 64; off <<= 1) {
      int u = __shfl_up(v, off);
      if (lane >= off) v += u;
    }
    int excl = __shfl_up(v, 1);
    if (lane == 0) excl = 0;
    if (i < nblk) blockSums[i] = excl + carry;
    carry += __shfl(v, 63);
  }
}

// K4c: add block offsets; init cursor; rowptr[N] = E
__global__ void k_scan_c(int* __restrict__ rowptr, const int* __restrict__ blockSums,
                         int* __restrict__ cursor, int N, int E) {
  int i = blockIdx.x * blockDim.x + threadIdx.x;
  if (i < N) {
    int v = rowptr[i] + blockSums[i / SCAN_ELEMS];
    rowptr[i] = v;
    cursor[i] = v;
  }
  if (i == 0) rowptr[N] = E;
}

// K5: scatter edges into CSR order; stash e_pre = s2[dst] + t[rel]
__global__ void k_scatter(const int* __restrict__ src, const int* __restrict__ dst,
                          const int* __restrict__ rel, const float* __restrict__ s2,
                          const float* __restrict__ tvec, int* __restrict__ cursor,
                          float* __restrict__ e_pre, int* __restrict__ edge_dst,
                          int* __restrict__ edge_rel, int E) {
  int i = blockIdx.x * blockDim.x + threadIdx.x;
  if (i >= E) return;
  int s = src[i], dd = dst[i], rr = rel[i];
  int pos = atomicAdd(&cursor[s], 1);
  e_pre[pos] = s2[dd] + tvec[rr];
  edge_dst[pos] = dd;
  edge_rel[pos] = rr;
}

// K6: one wave per node: segment softmax + weighted message accumulation
__global__ __launch_bounds__(256) void k_node(const float* __restrict__ Wh,
                                              const float* __restrict__ tbl,
                                              const float* __restrict__ s1,
                                              const int* __restrict__ rowptr,
                                              const float* __restrict__ e_pre,
                                              const int* __restrict__ edge_dst,
                                              const int* __restrict__ edge_rel,
                                              float* __restrict__ out, int N) {
  int wave = (int)((blockIdx.x * (size_t)blockDim.x + threadIdx.x) >> 6);
  int lane = threadIdx.x & 63;
  if (wave >= N) return;
  int start = rowptr[wave];
  int end = rowptr[wave + 1];
  if (end == start) {
    out[(size_t)wave * DD + lane] = 0.f;
    return;
  }
  float s1n = s1[wave];
  // phase 1: segment max (edge-parallel across lanes)
  float m = -3.402823466e+38f;
  for (int i = start + lane; i < end; i += 64) {
    float ev = s1n + e_pre[i];
    ev = (ev >= 0.f) ? ev : 0.2f * ev;
    m = fmaxf(m, ev);
  }
  for (int o = 32; o; o >>= 1) m = fmaxf(m, __shfl_xor(m, o));
  // phase 2: sum of exp
  float sum = 0.f;
  for (int i = start + lane; i < end; i += 64) {
    float ev = s1n + e_pre[i];
    ev = (ev >= 0.f) ? ev : 0.2f * ev;
    sum += __expf(ev - m);
  }
  for (int o = 32; o; o >>= 1) sum += __shfl_xor(sum, o);
  float rden = 1.f / (sum + 1e-12f);
  // phase 3: acc[lane] += w_e * (Wh[dst_e][lane] + tbl[rel_e][lane])
  float acc = 0.f;
  for (int c = start; c < end; c += 64) {
    int n = min(64, end - c);
    float wv = 0.f;
    int dv = 0, rv = 0;
    if (c + lane < end) {
      float ev = s1n + e_pre[c + lane];
      ev = (ev >= 0.f) ? ev : 0.2f * ev;
      wv = __expf(ev - m);
      dv = edge_dst[c + lane];
      rv = edge_rel[c + lane];
    }
    for (int j = 0; j < n; ++j) {
      float w = __shfl(wv, j);
      int dd = __shfl(dv, j);
      int rr = __shfl(rv, j);
      acc += w * (Wh[(size_t)dd * DD + lane] + tbl[rr * DD + lane]);
    }
  }
  out[(size_t)wave * DD + lane] = acc * rden;
}

extern "C" void kernel_launch(void* const* d_in, const int* in_sizes, int n_in,
                              void* d_out, int out_size, void* d_ws, size_t ws_size,
                              hipStream_t stream) {
  const float* H       = (const float*)d_in[0];
  const float* W_node  = (const float*)d_in[1];
  const float* W_rel   = (const float*)d_in[2];
  const float* attvec  = (const float*)d_in[3];
  const float* rel_emb = (const float*)d_in[4];
  const int*   src     = (const int*)d_in[5];
  const int*   dst     = (const int*)d_in[6];
  const int*   rel     = (const int*)d_in[7];

  int N = in_sizes[0] / DD;
  int E = in_sizes[5];
  int NR = in_sizes[4] / DD;

  char* ws = (char*)d_ws;
  size_t off = 0;
  auto alloc = [&](size_t bytes) -> char* {
    char* p = ws + off;
    off = (off + bytes + 255) & ~(size_t)255;
    return p;
  };
  float* Wh     = (float*)alloc((size_t)N * DD * 4);
  float* s1     = (float*)alloc((size_t)N * 4);
  float* s2     = (float*)alloc((size_t)N * 4);
  float* tbl    = (float*)alloc((size_t)NR * DD * 4);
  float* tvec   = (float*)alloc((size_t)NR * 4);
  int*   counts = (int*)alloc((size_t)N * 4);
  int*   rowptr = (int*)alloc((size_t)(N + 1) * 4);
  int*   cursor = (int*)alloc((size_t)N * 4);
  int nblk = (N + SCAN_ELEMS - 1) / SCAN_ELEMS;
  int*   bsums  = (int*)alloc((size_t)(nblk > 64 ? nblk : 64) * 4);
  float* e_pre  = (float*)alloc((size_t)E * 4);
  int*   edst   = (int*)alloc((size_t)E * 4);
  int*   erel   = (int*)alloc((size_t)E * 4);
  (void)ws_size;
  (void)n_in;
  (void)out_size;

  hipMemsetAsync(counts, 0, (size_t)N * 4, stream);

  k_gemm_wh<<<(N + 63) / 64, 256, 0, stream>>>(H, W_node, Wh, N);
  k_s12<<<(N + 3) / 4, 256, 0, stream>>>(Wh, attvec, s1, s2, N);
  k_rel<<<NR, 64, 0, stream>>>(rel_emb, W_rel, attvec, tbl, tvec);
  k_hist<<<(E + 255) / 256, 256, 0, stream>>>(src, counts, E);
  k_scan_a<<<nblk, 256, 0, stream>>>(counts, rowptr, bsums, N);
  k_scan_b<<<1, 64, 0, stream>>>(bsums, nblk);
  k_scan_c<<<(N + 255) / 256, 256, 0, stream>>>(rowptr, bsums, cursor, N, E);
  k_scatter<<<(E + 255) / 256, 256, 0, stream>>>(src, dst, rel, s2, tvec, cursor,
                                                 e_pre, edst, erel, E);
  k_node<<<(N + 3) / 4, 256, 0, stream>>>(Wh, tbl, s1, rowptr, e_pre, edst, erel,
                                          (float*)d_out, N);
}

// Round 4
// 312.851 us; speedup vs baseline: 1.0677x; 1.0677x over previous
//
#include <hip/hip_runtime.h>
#include <hip/hip_bf16.h>
#include <math.h>

#define DD 64
#define SCAN_ELEMS 2048

// K1: Wh = H @ W_node^T  (N x 64), fused epilogue: s1[n]=Wh[n].a[0:64], s2=Wh[n].a[64:128]
__global__ __launch_bounds__(256) void k_gemm_wh(const float* __restrict__ H,
                                                 const float* __restrict__ W,
                                                 const float* __restrict__ attvec,
                                                 float* __restrict__ Wh,
                                                 float* __restrict__ s1,
                                                 float* __restrict__ s2, int N) {
  __shared__ float Ws[64][65];  // Ws[k][j] = W[j][k]  (padded: conflict-free)
  __shared__ float Hs[64][64];
  int tid = threadIdx.x;
  int rowBase = blockIdx.x * 64;
  for (int i = tid; i < 4096; i += 256) {
    int j = i >> 6, k = i & 63;
    Ws[k][j] = W[i];
  }
  for (int i = tid; i < 4096; i += 256) {
    int r = i >> 6, k = i & 63;
    int gr = rowBase + r;
    Hs[r][k] = (gr < N) ? H[(size_t)gr * DD + k] : 0.f;
  }
  __syncthreads();
  int c = tid & 63;           // output column (lane)
  int wrow = (tid >> 6) * 16; // 16 rows per wave
  float acc[16];
#pragma unroll
  for (int i = 0; i < 16; ++i) acc[i] = 0.f;
  for (int k = 0; k < 64; ++k) {
    float wv = Ws[k][c];
#pragma unroll
    for (int rr = 0; rr < 16; ++rr) acc[rr] += Hs[wrow + rr][k] * wv;  // Hs: broadcast
  }
  float a1 = attvec[c], a2 = attvec[64 + c];
  for (int rr = 0; rr < 16; ++rr) {
    int gr = rowBase + wrow + rr;
    if (gr < N) Wh[(size_t)gr * DD + c] = acc[rr];
    // fused s1/s2: reduce acc[rr]*a1, acc[rr]*a2 across the wave
    float p1 = acc[rr] * a1;
    float p2 = acc[rr] * a2;
#pragma unroll
    for (int o = 32; o; o >>= 1) {
      p1 += __shfl_xor(p1, o);
      p2 += __shfl_xor(p2, o);
    }
    if (c == 0 && gr < N) { s1[gr] = p1; s2[gr] = p2; }
  }
}

// K2: tbl[r][d] = rel_emb[r] . W_rel[d],  t[r] = tbl[r] . a[128:192]
__global__ __launch_bounds__(64) void k_rel(const float* __restrict__ rel_emb,
                                            const float* __restrict__ Wrel,
                                            const float* __restrict__ attvec,
                                            float* __restrict__ tbl,
                                            float* __restrict__ tvec) {
  int r = blockIdx.x;
  int d = threadIdx.x;  // 64 threads
  __shared__ float re[64];
  re[d] = rel_emb[r * DD + d];
  __syncthreads();
  float acc = 0.f;
  for (int k = 0; k < DD; ++k) acc += re[k] * Wrel[d * DD + k];
  tbl[r * DD + d] = acc;
  float p = acc * attvec[128 + d];
  for (int o = 32; o; o >>= 1) p += __shfl_xor(p, o);
  if (d == 0) tvec[r] = p;
}

// K3: histogram of src
__global__ void k_hist(const int* __restrict__ src, int* __restrict__ counts, int E) {
  int i = blockIdx.x * blockDim.x + threadIdx.x;
  if (i < E) atomicAdd(&counts[src[i]], 1);
}

// K4a: per-block exclusive scan over 2048 elements; write partials + block sums
__global__ __launch_bounds__(256) void k_scan_a(const int* __restrict__ counts,
                                                int* __restrict__ partial,
                                                int* __restrict__ blockSums, int N) {
  __shared__ int ts[256];
  int tid = threadIdx.x;
  int base = blockIdx.x * SCAN_ELEMS + tid * 8;
  int v[8];
  int s = 0;
#pragma unroll
  for (int i = 0; i < 8; ++i) {
    int idx = base + i;
    v[i] = (idx < N) ? counts[idx] : 0;
    s += v[i];
  }
  ts[tid] = s;
  __syncthreads();
  for (int off = 1; off < 256; off <<= 1) {
    int val = (tid >= off) ? ts[tid - off] : 0;
    __syncthreads();
    ts[tid] += val;
    __syncthreads();
  }
  int thrExcl = (tid == 0) ? 0 : ts[tid - 1];
  if (tid == 255) blockSums[blockIdx.x] = ts[255];
  int run = thrExcl;
#pragma unroll
  for (int i = 0; i < 8; ++i) {
    int idx = base + i;
    if (idx < N) partial[idx] = run;
    run += v[i];
  }
}

// K4b: exclusive scan of block sums (single wave, chunked with carry)
__global__ __launch_bounds__(64) void k_scan_b(int* __restrict__ blockSums, int nblk) {
  int lane = threadIdx.x;
  int carry = 0;
  for (int b = 0; b < nblk; b += 64) {
    int i = b + lane;
    int v = (i < nblk) ? blockSums[i] : 0;
    for (int off = 1; off < 64; off <<= 1) {
      int u = __shfl_up(v, off);
      if (lane >= off) v += u;
    }
    int excl = __shfl_up(v, 1);
    if (lane == 0) excl = 0;
    if (i < nblk) blockSums[i] = excl + carry;
    carry += __shfl(v, 63);
  }
}

// K4c: add block offsets; init cursor; rowptr[N] = E
__global__ void k_scan_c(int* __restrict__ rowptr, const int* __restrict__ blockSums,
                         int* __restrict__ cursor, int N, int E) {
  int i = blockIdx.x * blockDim.x + threadIdx.x;
  if (i < N) {
    int v = rowptr[i] + blockSums[i / SCAN_ELEMS];
    rowptr[i] = v;
    cursor[i] = v;
  }
  if (i == 0) rowptr[N] = E;
}

// K5: scatter edges into CSR order as one 16B AoS record per edge:
//     rec = { bits(e_pre = s2[dst]+t[rel]), dst, rel, 0 }
__global__ void k_scatter(const int* __restrict__ src, const int* __restrict__ dst,
                          const int* __restrict__ rel, const float* __restrict__ s2,
                          const float* __restrict__ tvec, int* __restrict__ cursor,
                          int4* __restrict__ recs, int E) {
  int i = blockIdx.x * blockDim.x + threadIdx.x;
  if (i >= E) return;
  int s = src[i], dd = dst[i], rr = rel[i];
  int pos = atomicAdd(&cursor[s], 1);
  float ep = s2[dd] + tvec[rr];
  recs[pos] = make_int4(__float_as_int(ep), dd, rr, 0);
}

// K6: one wave per node: segment softmax + weighted message accumulation.
// Phase 3 processes 4 edges per step: wave split into 4 groups x 16 lanes;
// each group loads its edge's Wh/tbl row as float4 (16B/lane).
__global__ __launch_bounds__(256) void k_node(const float* __restrict__ Wh,
                                              const float* __restrict__ tbl,
                                              const float* __restrict__ s1,
                                              const int* __restrict__ rowptr,
                                              const int4* __restrict__ recs,
                                              float* __restrict__ out, int N) {
  int wave = (int)((blockIdx.x * (size_t)blockDim.x + threadIdx.x) >> 6);
  int lane = threadIdx.x & 63;
  if (wave >= N) return;
  int l = lane & 15;   // sub-lane within group (dim quad l -> dims 4l..4l+3)
  int g = lane >> 4;   // group = which of 4 concurrent edges
  int start = rowptr[wave];
  int end = rowptr[wave + 1];
  float4* outV = (float4*)(out + (size_t)wave * DD);
  if (end == start) {
    if (g == 0) outV[l] = make_float4(0.f, 0.f, 0.f, 0.f);
    return;
  }
  float s1n = s1[wave];
  // phase 1: segment max (edge-parallel across lanes)
  float m = -3.402823466e+38f;
  for (int i = start + lane; i < end; i += 64) {
    float ev = s1n + __int_as_float(recs[i].x);
    ev = (ev >= 0.f) ? ev : 0.2f * ev;
    m = fmaxf(m, ev);
  }
#pragma unroll
  for (int o = 32; o; o >>= 1) m = fmaxf(m, __shfl_xor(m, o));
  // phase 2: sum of exp
  float sum = 0.f;
  for (int i = start + lane; i < end; i += 64) {
    float ev = s1n + __int_as_float(recs[i].x);
    ev = (ev >= 0.f) ? ev : 0.2f * ev;
    sum += __expf(ev - m);
  }
#pragma unroll
  for (int o = 32; o; o >>= 1) sum += __shfl_xor(sum, o);
  float rden = 1.f / (sum + 1e-12f);
  // phase 3: acc4 += w_e * (WhV[dst_e][l] + tblV[rel_e][l]), 4 edges/step
  const float4* WhV = (const float4*)Wh;    // row stride: 16 float4
  const float4* tbV = (const float4*)tbl;
  float ax = 0.f, ay = 0.f, az = 0.f, aw = 0.f;
  for (int c = start; c < end; c += 64) {
    // each lane owns edge c+lane: compute weight + indices (0 if inactive)
    float wv = 0.f;
    int dv = 0, rv = 0;
    if (c + lane < end) {
      int4 rec = recs[c + lane];
      float ev = s1n + __int_as_float(rec.x);
      ev = (ev >= 0.f) ? ev : 0.2f * ev;
      wv = __expf(ev - m);
      dv = rec.y;
      rv = rec.z;
    }
    int n = min(64, end - c);
    int steps = (n + 3) >> 2;
    for (int jj = 0; jj < steps; ++jj) {
      int e = (jj << 2) + g;          // lane whose edge this group handles
      float w = __shfl(wv, e);        // w==0 for e>=n -> contributes nothing
      int dd = __shfl(dv, e);
      int rr = __shfl(rv, e);
      float4 row = WhV[(size_t)dd * 16 + l];
      float4 tb = tbV[rr * 16 + l];
      ax += w * (row.x + tb.x);
      ay += w * (row.y + tb.y);
      az += w * (row.z + tb.z);
      aw += w * (row.w + tb.w);
    }
  }
  // cross-group reduction: lanes {l, l+16, l+32, l+48} hold same dims
#pragma unroll
  for (int o = 32; o >= 16; o >>= 1) {
    ax += __shfl_xor(ax, o);
    ay += __shfl_xor(ay, o);
    az += __shfl_xor(az, o);
    aw += __shfl_xor(aw, o);
  }
  if (g == 0) outV[l] = make_float4(ax * rden, ay * rden, az * rden, aw * rden);
}

extern "C" void kernel_launch(void* const* d_in, const int* in_sizes, int n_in,
                              void* d_out, int out_size, void* d_ws, size_t ws_size,
                              hipStream_t stream) {
  const float* H       = (const float*)d_in[0];
  const float* W_node  = (const float*)d_in[1];
  const float* W_rel   = (const float*)d_in[2];
  const float* attvec  = (const float*)d_in[3];
  const float* rel_emb = (const float*)d_in[4];
  const int*   src     = (const int*)d_in[5];
  const int*   dst     = (const int*)d_in[6];
  const int*   rel     = (const int*)d_in[7];

  int N = in_sizes[0] / DD;
  int E = in_sizes[5];
  int NR = in_sizes[4] / DD;

  char* ws = (char*)d_ws;
  size_t off = 0;
  auto alloc = [&](size_t bytes) -> char* {
    char* p = ws + off;
    off = (off + bytes + 255) & ~(size_t)255;
    return p;
  };
  float* Wh     = (float*)alloc((size_t)N * DD * 4);
  float* s1     = (float*)alloc((size_t)N * 4);
  float* s2     = (float*)alloc((size_t)N * 4);
  float* tbl    = (float*)alloc((size_t)NR * DD * 4);
  float* tvec   = (float*)alloc((size_t)NR * 4);
  int*   counts = (int*)alloc((size_t)N * 4);
  int*   rowptr = (int*)alloc((size_t)(N + 1) * 4);
  int*   cursor = (int*)alloc((size_t)N * 4);
  int nblk = (N + SCAN_ELEMS - 1) / SCAN_ELEMS;
  int*   bsums  = (int*)alloc((size_t)(nblk > 64 ? nblk : 64) * 4);
  int4*  recs   = (int4*)alloc((size_t)E * 16);
  (void)ws_size;
  (void)n_in;
  (void)out_size;

  hipMemsetAsync(counts, 0, (size_t)N * 4, stream);

  k_gemm_wh<<<(N + 63) / 64, 256, 0, stream>>>(H, W_node, attvec, Wh, s1, s2, N);
  k_rel<<<NR, 64, 0, stream>>>(rel_emb, W_rel, attvec, tbl, tvec);
  k_hist<<<(E + 255) / 256, 256, 0, stream>>>(src, counts, E);
  k_scan_a<<<nblk, 256, 0, stream>>>(counts, rowptr, bsums, N);
  k_scan_b<<<1, 64, 0, stream>>>(bsums, nblk);
  k_scan_c<<<(N + 255) / 256, 256, 0, stream>>>(rowptr, bsums, cursor, N, E);
  k_scatter<<<(E + 255) / 256, 256, 0, stream>>>(src, dst, rel, s2, tvec, cursor,
                                                 recs, E);
  k_node<<<(N + 3) / 4, 256, 0, stream>>>(Wh, tbl, s1, rowptr, recs,
                                          (float*)d_out, N);
}